// Round 1
// baseline (1046.821 us; speedup 1.0000x reference)
//
#include <hip/hip_runtime.h>

#define DIN 128
#define HF  128
#define OUTF 32
#define NG  64

// ---------------- init ----------------
__global__ void k_init(int* __restrict__ deg, float* __restrict__ sums, int n, int m) {
    int i = blockIdx.x * blockDim.x + threadIdx.x;
    if (i < n) deg[i] = 0;
    if (i < m) sums[i] = 0.f;
}

// ---------------- degree ----------------
__global__ void k_deg(const int* __restrict__ dst, int* __restrict__ deg, int e) {
    int i = blockIdx.x * blockDim.x + threadIdx.x;
    if (i < e) atomicAdd(&deg[dst[i]], 1);
}

__global__ void k_dinv(const int* __restrict__ deg, float* __restrict__ dinv, int n) {
    int i = blockIdx.x * blockDim.x + threadIdx.x;
    if (i < n) dinv[i] = rsqrtf((float)deg[i] + 1.0f);   // +1 = self loop
}

// ---------------- exclusive scan (single block) ----------------
__global__ __launch_bounds__(1024) void k_scan(const int* __restrict__ deg,
                                               int* __restrict__ rowstart,
                                               int* __restrict__ cursor, int n) {
    __shared__ int s[1024];
    int t = threadIdx.x;
    int ch = (n + 1023) / 1024;
    int b = t * ch, e0 = min(b + ch, n);
    int sum = 0;
    for (int i = b; i < e0; ++i) sum += deg[i];
    s[t] = sum;
    __syncthreads();
    for (int off = 1; off < 1024; off <<= 1) {
        int v = (t >= off) ? s[t - off] : 0;
        __syncthreads();
        s[t] += v;
        __syncthreads();
    }
    int excl = (t == 0) ? 0 : s[t - 1];
    for (int i = b; i < e0; ++i) {
        rowstart[i] = excl;
        cursor[i] = excl;
        excl += deg[i];
    }
    if (t == 1023) rowstart[n] = s[1023];
}

// ---------------- counting-sort scatter: CSR by dst ----------------
__global__ void k_scatter(const int* __restrict__ src, const int* __restrict__ dst,
                          int* __restrict__ cursor, int* __restrict__ csr, int e) {
    int i = blockIdx.x * blockDim.x + threadIdx.x;
    if (i < e) {
        int d = dst[i];
        int pos = atomicAdd(&cursor[d], 1);
        csr[pos] = src[i];
    }
}

// ---------------- GEMM: ts[r] = (A[r] @ W) * dinv[r] ----------------
// A: [n,128], W: [128,128], out: [n,128]. 64-row tile, 256 threads, 8x4 micro.
__global__ __launch_bounds__(256) void k_gemm(const float* __restrict__ A,
                                              const float* __restrict__ W,
                                              const float* __restrict__ dinv,
                                              float* __restrict__ outp, int n) {
    __shared__ float As[32][68];      // transposed: As[k][row], padded (68*4=272B, 16B-mult)
    __shared__ float Ws[32 * 128];
    int t = threadIdx.x;
    int ty = t >> 5, tx = t & 31;
    int row0 = blockIdx.x * 64;
    float acc[8][4];
#pragma unroll
    for (int r = 0; r < 8; ++r)
#pragma unroll
        for (int c = 0; c < 4; ++c) acc[r][c] = 0.f;

    for (int kc = 0; kc < 128; kc += 32) {
        // stage A chunk (64 rows x 32 k) transposed
#pragma unroll
        for (int i = 0; i < 2; ++i) {
            int v = t * 2 + i;              // 0..511 float4 ids
            int row = v >> 3, k4 = (v & 7) << 2;
            float4 av = make_float4(0.f, 0.f, 0.f, 0.f);
            int gr = row0 + row;
            if (gr < n) av = *(const float4*)&A[gr * 128 + kc + k4];
            As[k4 + 0][row] = av.x;
            As[k4 + 1][row] = av.y;
            As[k4 + 2][row] = av.z;
            As[k4 + 3][row] = av.w;
        }
        // stage W chunk (32 k x 128 cols), contiguous
#pragma unroll
        for (int i = 0; i < 4; ++i) {
            int v = i * 256 + t;            // 0..1023 float4 ids
            *(float4*)&Ws[v * 4] = *(const float4*)&W[kc * 128 + v * 4];
        }
        __syncthreads();
#pragma unroll
        for (int k = 0; k < 32; ++k) {
            float4 alo = *(float4*)&As[k][ty * 8];
            float4 ahi = *(float4*)&As[k][ty * 8 + 4];
            float4 bv  = *(float4*)&Ws[k * 128 + tx * 4];
            float a[8] = {alo.x, alo.y, alo.z, alo.w, ahi.x, ahi.y, ahi.z, ahi.w};
#pragma unroll
            for (int r = 0; r < 8; ++r) {
                acc[r][0] += a[r] * bv.x;
                acc[r][1] += a[r] * bv.y;
                acc[r][2] += a[r] * bv.z;
                acc[r][3] += a[r] * bv.w;
            }
        }
        __syncthreads();
    }
#pragma unroll
    for (int r = 0; r < 8; ++r) {
        int row = row0 + ty * 8 + r;
        if (row < n) {
            float d = dinv[row];
            float4 o = make_float4(acc[r][0] * d, acc[r][1] * d, acc[r][2] * d, acc[r][3] * d);
            *(float4*)&outp[row * 128 + tx * 4] = o;
        }
    }
}

// ---------------- pull-aggregate: out[i] = relu?((ts[i] + sum ts[csr]) * dinv[i] + b) ----
__global__ __launch_bounds__(256) void k_pull(const float* __restrict__ ts,
                                              const int* __restrict__ csr,
                                              const int* __restrict__ rowstart,
                                              const float* __restrict__ dinv,
                                              const float* __restrict__ bias,
                                              float* __restrict__ outp, int n, int do_relu) {
    int wid = (int)((blockIdx.x * blockDim.x + threadIdx.x) >> 6);
    int lane = threadIdx.x & 63;
    if (wid >= n) return;
    int f = lane * 2;
    float2 acc = *(const float2*)&ts[(size_t)wid * 128 + f];   // self loop term
    int e1 = rowstart[wid + 1];
    int e = rowstart[wid];
    for (; e + 4 <= e1; e += 4) {
        int s0 = csr[e], s1 = csr[e + 1], s2 = csr[e + 2], s3 = csr[e + 3];
        float2 v0 = *(const float2*)&ts[(size_t)s0 * 128 + f];
        float2 v1 = *(const float2*)&ts[(size_t)s1 * 128 + f];
        float2 v2 = *(const float2*)&ts[(size_t)s2 * 128 + f];
        float2 v3 = *(const float2*)&ts[(size_t)s3 * 128 + f];
        acc.x += v0.x + v1.x + v2.x + v3.x;
        acc.y += v0.y + v1.y + v2.y + v3.y;
    }
    for (; e < e1; ++e) {
        int s = csr[e];
        float2 v = *(const float2*)&ts[(size_t)s * 128 + f];
        acc.x += v.x;
        acc.y += v.y;
    }
    float d = dinv[wid];
    float ox = acc.x * d + bias[f];
    float oy = acc.y * d + bias[f + 1];
    if (do_relu) { ox = fmaxf(ox, 0.f); oy = fmaxf(oy, 0.f); }
    float2 o = make_float2(ox, oy);
    *(float2*)&outp[(size_t)wid * 128 + f] = o;
}

// ---------------- mean-pool: sums[g][f] += h[i][f] (batch sorted) ----------------
__global__ __launch_bounds__(128) void k_pool(const float* __restrict__ h,
                                              const int* __restrict__ batch,
                                              float* __restrict__ sums, int n) {
    int f = threadIdx.x;                    // 0..127
    int n0 = blockIdx.x * 64;
    int n1 = min(n0 + 64, n);
    float run = 0.f;
    int cur = batch[n0];
    for (int i = n0; i < n1; ++i) {
        int g = batch[i];
        if (g != cur) {
            atomicAdd(&sums[cur * 128 + f], run);
            run = 0.f;
            cur = g;
        }
        run += h[(size_t)i * 128 + f];
    }
    atomicAdd(&sums[cur * 128 + f], run);
}

__global__ void k_counts(const int* __restrict__ batch, float* __restrict__ counts, int n) {
    int g = threadIdx.x;                    // 0..63
    int lo = 0, hi = n;
    while (lo < hi) { int mid = (lo + hi) >> 1; if (batch[mid] < g) lo = mid + 1; else hi = mid; }
    int a = lo;
    lo = 0; hi = n;
    int key = g + 1;
    while (lo < hi) { int mid = (lo + hi) >> 1; if (batch[mid] < key) lo = mid + 1; else hi = mid; }
    counts[g] = (float)(lo - a);
}

// ---------------- head MLP (single block) ----------------
__global__ __launch_bounds__(512) void k_head(const float* __restrict__ sums,
                                              const float* __restrict__ counts,
                                              const float* __restrict__ Wo1,
                                              const float* __restrict__ bo1,
                                              const float* __restrict__ Wo2,
                                              const float* __restrict__ bo2,
                                              float* __restrict__ outp) {
    __shared__ float P[NG * 128];
    __shared__ float Z[NG * 64];
    int t = threadIdx.x;
    for (int i = t; i < NG * 128; i += 512) {
        int g = i >> 7;
        P[i] = sums[i] / fmaxf(counts[g], 1.f);
    }
    __syncthreads();
    for (int i = t; i < NG * 64; i += 512) {
        int g = i >> 6, c = i & 63;
        float s = bo1[c];
        for (int k = 0; k < 128; ++k) s += P[g * 128 + k] * Wo1[k * 64 + c];
        Z[i] = fmaxf(s, 0.f);
    }
    __syncthreads();
    for (int i = t; i < NG * OUTF; i += 512) {
        int g = i >> 5, c = i & 31;
        float s = bo2[c];
        for (int k = 0; k < 64; ++k) s += Z[g * 64 + k] * Wo2[k * 32 + c];
        outp[i] = s;
    }
}

extern "C" void kernel_launch(void* const* d_in, const int* in_sizes, int n_in,
                              void* d_out, int out_size, void* d_ws, size_t ws_size,
                              hipStream_t stream) {
    const float* x    = (const float*)d_in[0];
    const int*   ei   = (const int*)d_in[1];
    const int*   batch= (const int*)d_in[2];
    const float* W1   = (const float*)d_in[3];
    const float* b1   = (const float*)d_in[4];
    const float* W2   = (const float*)d_in[5];
    const float* b2   = (const float*)d_in[6];
    const float* W3   = (const float*)d_in[7];
    const float* b3   = (const float*)d_in[8];
    const float* Wo1  = (const float*)d_in[9];
    const float* bo1  = (const float*)d_in[10];
    const float* Wo2  = (const float*)d_in[11];
    const float* bo2  = (const float*)d_in[12];

    int n = in_sizes[0] / DIN;
    int e = in_sizes[1] / 2;
    const int* esrc = ei;
    const int* edst = ei + e;

    // workspace layout (all 256B-aligned)
    char* ws = (char*)d_ws;
    auto align = [](size_t v) { return (v + 255) & ~(size_t)255; };
    size_t off = 0;
    int*   deg      = (int*)(ws + off); off = align(off + sizeof(int) * n);
    int*   rowstart = (int*)(ws + off); off = align(off + sizeof(int) * (n + 1));
    int*   cursor   = (int*)(ws + off); off = align(off + sizeof(int) * n);
    int*   csr      = (int*)(ws + off); off = align(off + sizeof(int) * e);
    float* dinv     = (float*)(ws + off); off = align(off + sizeof(float) * n);
    float* buf0     = (float*)(ws + off); off = align(off + sizeof(float) * (size_t)n * HF);
    float* buf1     = (float*)(ws + off); off = align(off + sizeof(float) * (size_t)n * HF);
    float* sums     = (float*)(ws + off); off = align(off + sizeof(float) * NG * HF);
    float* counts   = (float*)(ws + off); off = align(off + sizeof(float) * NG);

    int tb = 256;
    int gb_n = (n + tb - 1) / tb;
    int gb_e = (e + tb - 1) / tb;

    k_init<<<gb_n, tb, 0, stream>>>(deg, sums, n, NG * HF);
    k_deg<<<gb_e, tb, 0, stream>>>(edst, deg, e);
    k_dinv<<<gb_n, tb, 0, stream>>>(deg, dinv, n);
    k_scan<<<1, 1024, 0, stream>>>(deg, rowstart, cursor, n);
    k_scatter<<<gb_e, tb, 0, stream>>>(esrc, edst, cursor, csr, e);

    int gemm_grid = (n + 63) / 64;
    int pull_grid = (int)(((size_t)n * 64 + tb - 1) / tb);

    // conv1
    k_gemm<<<gemm_grid, 256, 0, stream>>>(x, W1, dinv, buf1, n);
    k_pull<<<pull_grid, 256, 0, stream>>>(buf1, csr, rowstart, dinv, b1, buf0, n, 1);
    // conv2
    k_gemm<<<gemm_grid, 256, 0, stream>>>(buf0, W2, dinv, buf1, n);
    k_pull<<<pull_grid, 256, 0, stream>>>(buf1, csr, rowstart, dinv, b2, buf0, n, 1);
    // conv3
    k_gemm<<<gemm_grid, 256, 0, stream>>>(buf0, W3, dinv, buf1, n);
    k_pull<<<pull_grid, 256, 0, stream>>>(buf1, csr, rowstart, dinv, b3, buf0, n, 0);

    // pooling + head
    k_pool<<<(n + 63) / 64, 128, 0, stream>>>(buf0, batch, sums, n);
    k_counts<<<1, 64, 0, stream>>>(batch, counts, n);
    k_head<<<1, 512, 0, stream>>>(sums, counts, Wo1, bo1, Wo2, bo2, (float*)d_out);
}

// Round 2
// 852.025 us; speedup vs baseline: 1.2286x; 1.2286x over previous
//
#include <hip/hip_runtime.h>

#define DIN 128
#define HF  128
#define OUTF 32
#define NG  64
#define SCH 2048   // scan elements per block (8 per thread, 256 threads)

// ---------------- init ----------------
__global__ void k_init(int* __restrict__ deg, float* __restrict__ sums, int n, int m) {
    int i = blockIdx.x * blockDim.x + threadIdx.x;
    if (i < n) deg[i] = 0;
    if (i < m) sums[i] = 0.f;
}

// ---------------- degree ----------------
__global__ void k_deg(const int* __restrict__ dst, int* __restrict__ deg, int e) {
    int i = blockIdx.x * blockDim.x + threadIdx.x;
    if (i < e) atomicAdd(&deg[dst[i]], 1);
}

__global__ void k_dinv(const int* __restrict__ deg, float* __restrict__ dinv, int n) {
    int i = blockIdx.x * blockDim.x + threadIdx.x;
    if (i < n) dinv[i] = rsqrtf((float)deg[i] + 1.0f);   // +1 = self loop
}

// ---------------- multi-block exclusive scan ----------------
// pass 1: per-block sums
__global__ __launch_bounds__(256) void k_blksum(const int* __restrict__ deg,
                                                int* __restrict__ bsum, int n) {
    __shared__ int s[256];
    int b = blockIdx.x, t = threadIdx.x;
    int base = b * SCH + t * 8;
    int sum = 0;
    if (base + 8 <= n) {
        int4 a = *(const int4*)&deg[base];
        int4 c = *(const int4*)&deg[base + 4];
        sum = a.x + a.y + a.z + a.w + c.x + c.y + c.z + c.w;
    } else {
        for (int i = base; i < min(base + 8, n); ++i) sum += deg[i];
    }
    s[t] = sum;
    __syncthreads();
    for (int off = 128; off > 0; off >>= 1) {
        if (t < off) s[t] += s[t + off];
        __syncthreads();
    }
    if (t == 0) bsum[b] = s[0];
}

// pass 2: scan block sums (nb <= 256), also writes rowstart[n] = total
__global__ __launch_bounds__(256) void k_scanb(const int* __restrict__ bsum,
                                               int* __restrict__ boff, int nb,
                                               int* __restrict__ rowstart, int n) {
    __shared__ int s[256];
    int t = threadIdx.x;
    int v = (t < nb) ? bsum[t] : 0;
    s[t] = v;
    __syncthreads();
    for (int off = 1; off < 256; off <<= 1) {
        int u = (t >= off) ? s[t - off] : 0;
        __syncthreads();
        s[t] += u;
        __syncthreads();
    }
    if (t < nb) boff[t] = s[t] - v;          // exclusive
    if (t == 255) rowstart[n] = s[255];      // total = e
}

// pass 3: per-block exclusive scan + write rowstart/cursor (int4 stores)
__global__ __launch_bounds__(256) void k_fixup(const int* __restrict__ deg,
                                               const int* __restrict__ boff,
                                               int* __restrict__ rowstart,
                                               int* __restrict__ cursor, int n) {
    __shared__ int s[256];
    int b = blockIdx.x, t = threadIdx.x;
    int base = b * SCH + t * 8;
    int d[8];
    int sum = 0;
#pragma unroll
    for (int i = 0; i < 8; ++i) {
        int idx = base + i;
        d[i] = (idx < n) ? deg[idx] : 0;
        sum += d[i];
    }
    s[t] = sum;
    __syncthreads();
    for (int off = 1; off < 256; off <<= 1) {
        int u = (t >= off) ? s[t - off] : 0;
        __syncthreads();
        s[t] += u;
        __syncthreads();
    }
    int excl = boff[b] + s[t] - sum;
    int r[8];
#pragma unroll
    for (int i = 0; i < 8; ++i) { r[i] = excl; excl += d[i]; }
    if (base + 8 <= n) {
        *(int4*)&rowstart[base]     = make_int4(r[0], r[1], r[2], r[3]);
        *(int4*)&rowstart[base + 4] = make_int4(r[4], r[5], r[6], r[7]);
        *(int4*)&cursor[base]       = make_int4(r[0], r[1], r[2], r[3]);
        *(int4*)&cursor[base + 4]   = make_int4(r[4], r[5], r[6], r[7]);
    } else {
        for (int i = 0; i < 8; ++i) {
            int idx = base + i;
            if (idx < n) { rowstart[idx] = r[i]; cursor[idx] = r[i]; }
        }
    }
}

// ---------------- counting-sort scatter: CSR by dst ----------------
__global__ void k_scatter(const int* __restrict__ src, const int* __restrict__ dst,
                          int* __restrict__ cursor, int* __restrict__ csr, int e) {
    int i = blockIdx.x * blockDim.x + threadIdx.x;
    if (i < e) {
        int d = dst[i];
        int pos = atomicAdd(&cursor[d], 1);
        csr[pos] = src[i];
    }
}

// ---------------- GEMM: ts[r] = (A[r] @ W) * dinv[r] ----------------
__global__ __launch_bounds__(256) void k_gemm(const float* __restrict__ A,
                                              const float* __restrict__ W,
                                              const float* __restrict__ dinv,
                                              float* __restrict__ outp, int n) {
    __shared__ float As[32][68];
    __shared__ float Ws[32 * 128];
    int t = threadIdx.x;
    int ty = t >> 5, tx = t & 31;
    int row0 = blockIdx.x * 64;
    float acc[8][4];
#pragma unroll
    for (int r = 0; r < 8; ++r)
#pragma unroll
        for (int c = 0; c < 4; ++c) acc[r][c] = 0.f;

    for (int kc = 0; kc < 128; kc += 32) {
#pragma unroll
        for (int i = 0; i < 2; ++i) {
            int v = t * 2 + i;
            int row = v >> 3, k4 = (v & 7) << 2;
            float4 av = make_float4(0.f, 0.f, 0.f, 0.f);
            int gr = row0 + row;
            if (gr < n) av = *(const float4*)&A[gr * 128 + kc + k4];
            As[k4 + 0][row] = av.x;
            As[k4 + 1][row] = av.y;
            As[k4 + 2][row] = av.z;
            As[k4 + 3][row] = av.w;
        }
#pragma unroll
        for (int i = 0; i < 4; ++i) {
            int v = i * 256 + t;
            *(float4*)&Ws[v * 4] = *(const float4*)&W[kc * 128 + v * 4];
        }
        __syncthreads();
#pragma unroll
        for (int k = 0; k < 32; ++k) {
            float4 alo = *(float4*)&As[k][ty * 8];
            float4 ahi = *(float4*)&As[k][ty * 8 + 4];
            float4 bv  = *(float4*)&Ws[k * 128 + tx * 4];
            float a[8] = {alo.x, alo.y, alo.z, alo.w, ahi.x, ahi.y, ahi.z, ahi.w};
#pragma unroll
            for (int r = 0; r < 8; ++r) {
                acc[r][0] += a[r] * bv.x;
                acc[r][1] += a[r] * bv.y;
                acc[r][2] += a[r] * bv.z;
                acc[r][3] += a[r] * bv.w;
            }
        }
        __syncthreads();
    }
#pragma unroll
    for (int r = 0; r < 8; ++r) {
        int row = row0 + ty * 8 + r;
        if (row < n) {
            float d = dinv[row];
            float4 o = make_float4(acc[r][0] * d, acc[r][1] * d, acc[r][2] * d, acc[r][3] * d);
            *(float4*)&outp[row * 128 + tx * 4] = o;
        }
    }
}

// ---------------- pull-aggregate ----------------
__global__ __launch_bounds__(256) void k_pull(const float* __restrict__ ts,
                                              const int* __restrict__ csr,
                                              const int* __restrict__ rowstart,
                                              const float* __restrict__ dinv,
                                              const float* __restrict__ bias,
                                              float* __restrict__ outp, int n, int do_relu) {
    int wid = (int)((blockIdx.x * blockDim.x + threadIdx.x) >> 6);
    int lane = threadIdx.x & 63;
    if (wid >= n) return;
    int f = lane * 2;
    float2 acc = *(const float2*)&ts[(size_t)wid * 128 + f];
    int e1 = rowstart[wid + 1];
    int e = rowstart[wid];
    for (; e + 4 <= e1; e += 4) {
        int s0 = csr[e], s1 = csr[e + 1], s2 = csr[e + 2], s3 = csr[e + 3];
        float2 v0 = *(const float2*)&ts[(size_t)s0 * 128 + f];
        float2 v1 = *(const float2*)&ts[(size_t)s1 * 128 + f];
        float2 v2 = *(const float2*)&ts[(size_t)s2 * 128 + f];
        float2 v3 = *(const float2*)&ts[(size_t)s3 * 128 + f];
        acc.x += v0.x + v1.x + v2.x + v3.x;
        acc.y += v0.y + v1.y + v2.y + v3.y;
    }
    for (; e < e1; ++e) {
        int s = csr[e];
        float2 v = *(const float2*)&ts[(size_t)s * 128 + f];
        acc.x += v.x;
        acc.y += v.y;
    }
    float d = dinv[wid];
    float ox = acc.x * d + bias[f];
    float oy = acc.y * d + bias[f + 1];
    if (do_relu) { ox = fmaxf(ox, 0.f); oy = fmaxf(oy, 0.f); }
    *(float2*)&outp[(size_t)wid * 128 + f] = make_float2(ox, oy);
}

// ---------------- mean-pool ----------------
__global__ __launch_bounds__(128) void k_pool(const float* __restrict__ h,
                                              const int* __restrict__ batch,
                                              float* __restrict__ sums, int n) {
    int f = threadIdx.x;
    int n0 = blockIdx.x * 64;
    int n1 = min(n0 + 64, n);
    float run = 0.f;
    int cur = batch[n0];
    for (int i = n0; i < n1; ++i) {
        int g = batch[i];
        if (g != cur) {
            atomicAdd(&sums[cur * 128 + f], run);
            run = 0.f;
            cur = g;
        }
        run += h[(size_t)i * 128 + f];
    }
    atomicAdd(&sums[cur * 128 + f], run);
}

__global__ void k_counts(const int* __restrict__ batch, float* __restrict__ counts, int n) {
    int g = threadIdx.x;
    int lo = 0, hi = n;
    while (lo < hi) { int mid = (lo + hi) >> 1; if (batch[mid] < g) lo = mid + 1; else hi = mid; }
    int a = lo;
    lo = 0; hi = n;
    int key = g + 1;
    while (lo < hi) { int mid = (lo + hi) >> 1; if (batch[mid] < key) lo = mid + 1; else hi = mid; }
    counts[g] = (float)(lo - a);
}

// ---------------- head MLP ----------------
__global__ __launch_bounds__(512) void k_head(const float* __restrict__ sums,
                                              const float* __restrict__ counts,
                                              const float* __restrict__ Wo1,
                                              const float* __restrict__ bo1,
                                              const float* __restrict__ Wo2,
                                              const float* __restrict__ bo2,
                                              float* __restrict__ outp) {
    __shared__ float P[NG * 128];
    __shared__ float Z[NG * 64];
    int t = threadIdx.x;
    for (int i = t; i < NG * 128; i += 512) {
        int g = i >> 7;
        P[i] = sums[i] / fmaxf(counts[g], 1.f);
    }
    __syncthreads();
    for (int i = t; i < NG * 64; i += 512) {
        int g = i >> 6, c = i & 63;
        float s = bo1[c];
        for (int k = 0; k < 128; ++k) s += P[g * 128 + k] * Wo1[k * 64 + c];
        Z[i] = fmaxf(s, 0.f);
    }
    __syncthreads();
    for (int i = t; i < NG * OUTF; i += 512) {
        int g = i >> 5, c = i & 31;
        float s = bo2[c];
        for (int k = 0; k < 64; ++k) s += Z[g * 64 + k] * Wo2[k * 32 + c];
        outp[i] = s;
    }
}

extern "C" void kernel_launch(void* const* d_in, const int* in_sizes, int n_in,
                              void* d_out, int out_size, void* d_ws, size_t ws_size,
                              hipStream_t stream) {
    const float* x    = (const float*)d_in[0];
    const int*   ei   = (const int*)d_in[1];
    const int*   batch= (const int*)d_in[2];
    const float* W1   = (const float*)d_in[3];
    const float* b1   = (const float*)d_in[4];
    const float* W2   = (const float*)d_in[5];
    const float* b2   = (const float*)d_in[6];
    const float* W3   = (const float*)d_in[7];
    const float* b3   = (const float*)d_in[8];
    const float* Wo1  = (const float*)d_in[9];
    const float* bo1  = (const float*)d_in[10];
    const float* Wo2  = (const float*)d_in[11];
    const float* bo2  = (const float*)d_in[12];

    int n = in_sizes[0] / DIN;
    int e = in_sizes[1] / 2;
    const int* esrc = ei;
    const int* edst = ei + e;

    char* ws = (char*)d_ws;
    auto align = [](size_t v) { return (v + 255) & ~(size_t)255; };
    size_t off = 0;
    int*   deg      = (int*)(ws + off); off = align(off + sizeof(int) * n);
    int*   rowstart = (int*)(ws + off); off = align(off + sizeof(int) * (n + 1));
    int*   cursor   = (int*)(ws + off); off = align(off + sizeof(int) * n);
    int*   csr      = (int*)(ws + off); off = align(off + sizeof(int) * e);
    float* dinv     = (float*)(ws + off); off = align(off + sizeof(float) * n);
    float* buf0     = (float*)(ws + off); off = align(off + sizeof(float) * (size_t)n * HF);
    float* buf1     = (float*)(ws + off); off = align(off + sizeof(float) * (size_t)n * HF);
    float* sums     = (float*)(ws + off); off = align(off + sizeof(float) * NG * HF);
    float* counts   = (float*)(ws + off); off = align(off + sizeof(float) * NG);
    int*   bsum     = (int*)(ws + off); off = align(off + sizeof(int) * 512);
    int*   boff     = (int*)(ws + off); off = align(off + sizeof(int) * 512);

    int tb = 256;
    int gb_n = (n + tb - 1) / tb;
    int gb_e = (e + tb - 1) / tb;
    int nb = (n + SCH - 1) / SCH;   // 49 blocks for n=100000

    k_init<<<gb_n, tb, 0, stream>>>(deg, sums, n, NG * HF);
    k_deg<<<gb_e, tb, 0, stream>>>(edst, deg, e);
    k_dinv<<<gb_n, tb, 0, stream>>>(deg, dinv, n);
    k_blksum<<<nb, 256, 0, stream>>>(deg, bsum, n);
    k_scanb<<<1, 256, 0, stream>>>(bsum, boff, nb, rowstart, n);
    k_fixup<<<nb, 256, 0, stream>>>(deg, boff, rowstart, cursor, n);
    k_scatter<<<gb_e, tb, 0, stream>>>(esrc, edst, cursor, csr, e);

    int gemm_grid = (n + 63) / 64;
    int pull_grid = (int)(((size_t)n * 64 + tb - 1) / tb);

    k_gemm<<<gemm_grid, 256, 0, stream>>>(x, W1, dinv, buf1, n);
    k_pull<<<pull_grid, 256, 0, stream>>>(buf1, csr, rowstart, dinv, b1, buf0, n, 1);
    k_gemm<<<gemm_grid, 256, 0, stream>>>(buf0, W2, dinv, buf1, n);
    k_pull<<<pull_grid, 256, 0, stream>>>(buf1, csr, rowstart, dinv, b2, buf0, n, 1);
    k_gemm<<<gemm_grid, 256, 0, stream>>>(buf0, W3, dinv, buf1, n);
    k_pull<<<pull_grid, 256, 0, stream>>>(buf1, csr, rowstart, dinv, b3, buf0, n, 0);

    k_pool<<<(n + 63) / 64, 128, 0, stream>>>(buf0, batch, sums, n);
    k_counts<<<1, 64, 0, stream>>>(batch, counts, n);
    k_head<<<1, 512, 0, stream>>>(sums, counts, Wo1, bo1, Wo2, bo2, (float*)d_out);
}

// Round 4
// 629.974 us; speedup vs baseline: 1.6617x; 1.3525x over previous
//
#include <hip/hip_runtime.h>

#define DIN 128
#define HF  128
#define OUTF 32
#define NG  64
#define SCH 2048     // scan elements per block
#define NPB 512      // nodes per bucket
#define BSHIFT 9
#define P1_VPT 16    // edges per thread in pass1
#define P2_CAP 14336 // staged csr span capacity (ints) per bucket

typedef unsigned int uint32;

static __device__ __forceinline__ unsigned short f2bf(float f) {
    unsigned int u = __float_as_uint(f);
    u = (u + 0x7FFFu + ((u >> 16) & 1u)) >> 16;   // RNE
    return (unsigned short)u;
}

// ---------------- init ----------------
__global__ void k_init(int* __restrict__ deg, float* __restrict__ sums, int n, int m) {
    int i = blockIdx.x * blockDim.x + threadIdx.x;
    if (i < n) deg[i] = 0;
    if (i < m) sums[i] = 0.f;
}

// ---------------- degree ----------------
__global__ void k_deg(const int* __restrict__ dst, int* __restrict__ deg, int e) {
    int i = blockIdx.x * blockDim.x + threadIdx.x;
    if (i < e) atomicAdd(&deg[dst[i]], 1);
}

__global__ void k_dinv(const int* __restrict__ deg, float* __restrict__ dinv, int n) {
    int i = blockIdx.x * blockDim.x + threadIdx.x;
    if (i < n) dinv[i] = rsqrtf((float)deg[i] + 1.0f);   // +1 = self loop
}

// ---------------- multi-block exclusive scan (deg -> rowstart) ----------------
__global__ __launch_bounds__(256) void k_blksum(const int* __restrict__ deg,
                                                int* __restrict__ bsum, int n) {
    __shared__ int s[256];
    int b = blockIdx.x, t = threadIdx.x;
    int base = b * SCH + t * 8;
    int sum = 0;
    if (base + 8 <= n) {
        int4 a = *(const int4*)&deg[base];
        int4 c = *(const int4*)&deg[base + 4];
        sum = a.x + a.y + a.z + a.w + c.x + c.y + c.z + c.w;
    } else {
        for (int i = base; i < min(base + 8, n); ++i) sum += deg[i];
    }
    s[t] = sum;
    __syncthreads();
    for (int off = 128; off > 0; off >>= 1) {
        if (t < off) s[t] += s[t + off];
        __syncthreads();
    }
    if (t == 0) bsum[b] = s[0];
}

__global__ __launch_bounds__(256) void k_scanb(const int* __restrict__ bsum,
                                               int* __restrict__ boff, int nb,
                                               int* __restrict__ rowstart, int n) {
    __shared__ int s[256];
    int t = threadIdx.x;
    int v = (t < nb) ? bsum[t] : 0;
    s[t] = v;
    __syncthreads();
    for (int off = 1; off < 256; off <<= 1) {
        int u = (t >= off) ? s[t - off] : 0;
        __syncthreads();
        s[t] += u;
        __syncthreads();
    }
    if (t < nb) boff[t] = s[t] - v;
    if (t == 255) rowstart[n] = s[255];
}

__global__ __launch_bounds__(256) void k_fixup(const int* __restrict__ deg,
                                               const int* __restrict__ boff,
                                               int* __restrict__ rowstart, int n) {
    __shared__ int s[256];
    int b = blockIdx.x, t = threadIdx.x;
    int base = b * SCH + t * 8;
    int d[8];
    int sum = 0;
#pragma unroll
    for (int i = 0; i < 8; ++i) {
        int idx = base + i;
        d[i] = (idx < n) ? deg[idx] : 0;
        sum += d[i];
    }
    s[t] = sum;
    __syncthreads();
    for (int off = 1; off < 256; off <<= 1) {
        int u = (t >= off) ? s[t - off] : 0;
        __syncthreads();
        s[t] += u;
        __syncthreads();
    }
    int excl = boff[b] + s[t] - sum;
    int r[8];
#pragma unroll
    for (int i = 0; i < 8; ++i) { r[i] = excl; excl += d[i]; }
    if (base + 8 <= n) {
        *(int4*)&rowstart[base]     = make_int4(r[0], r[1], r[2], r[3]);
        *(int4*)&rowstart[base + 4] = make_int4(r[4], r[5], r[6], r[7]);
    } else {
        for (int i = 0; i < 8; ++i) {
            int idx = base + i;
            if (idx < n) rowstart[idx] = r[i];
        }
    }
}

// bucket cursors = rowstart at bucket boundaries
__global__ void k_binit(const int* __restrict__ rowstart, int* __restrict__ bcur,
                        int n, int nb) {
    int b = blockIdx.x * blockDim.x + threadIdx.x;
    if (b < nb) bcur[b] = rowstart[min(b << BSHIFT, n)];
}

// ---------------- pass1: coarse bucket (dst>>9), LDS-ranked grouped writes ----
__global__ __launch_bounds__(256) void k_pass1(const int* __restrict__ esrc,
                                               const int* __restrict__ edst,
                                               int* __restrict__ bcur,
                                               int2* __restrict__ ebuf, int e) {
    __shared__ int hist[256];
    __shared__ int base[256];
    int t = threadIdx.x;
    int c0 = blockIdx.x * (256 * P1_VPT);
    hist[t] = 0;
    __syncthreads();
    int s[P1_VPT], d[P1_VPT], r[P1_VPT];
#pragma unroll
    for (int i = 0; i < P1_VPT; ++i) {
        int idx = c0 + t + i * 256;
        if (idx < e) {
            s[i] = esrc[idx];
            d[i] = edst[idx];
            r[i] = atomicAdd(&hist[d[i] >> BSHIFT], 1);
        }
    }
    __syncthreads();
    int cnt = hist[t];
    base[t] = (cnt > 0) ? atomicAdd(&bcur[t], cnt) : 0;
    __syncthreads();
#pragma unroll
    for (int i = 0; i < P1_VPT; ++i) {
        int idx = c0 + t + i * 256;
        if (idx < e) ebuf[base[d[i] >> BSHIFT] + r[i]] = make_int2(s[i], d[i]);
    }
}

// ---------------- pass2: per-bucket LDS-staged fine scatter, coalesced csr ----
__global__ __launch_bounds__(256) void k_pass2(const int2* __restrict__ ebuf,
                                               const int* __restrict__ rowstart,
                                               int* __restrict__ csr, int n) {
    __shared__ int lcur[NPB];
    __shared__ int lbuf[P2_CAP];
    int b = blockIdx.x;
    int node0 = b << BSHIFT;
    int node1 = min(node0 + NPB, n);
    int t = threadIdx.x;
    int bbase = rowstart[node0];
    int bend = rowstart[node1];
    int span = bend - bbase;
    for (int j = t; j < node1 - node0; j += 256) lcur[j] = rowstart[node0 + j] - bbase;
    __syncthreads();
    if (span <= P2_CAP) {
        for (int i = t; i < span; i += 256) {
            int2 ed = ebuf[bbase + i];
            int lp = atomicAdd(&lcur[ed.y - node0], 1);
            lbuf[lp] = ed.x;
        }
        __syncthreads();
        for (int i = t; i < span; i += 256) csr[bbase + i] = lbuf[i];
    } else {  // safety fallback (never expected for this distribution)
        for (int i = t; i < span; i += 256) {
            int2 ed = ebuf[bbase + i];
            int lp = atomicAdd(&lcur[ed.y - node0], 1);
            csr[bbase + lp] = ed.x;
        }
    }
}

// ---------------- GEMM: tb[r] = bf16((A[r] @ W) * dinv[r]) ----------------
__global__ __launch_bounds__(256) void k_gemm(const float* __restrict__ A,
                                              const float* __restrict__ W,
                                              const float* __restrict__ dinv,
                                              unsigned short* __restrict__ tb, int n) {
    __shared__ float As[32][68];
    __shared__ float Ws[32 * 128];
    int t = threadIdx.x;
    int ty = t >> 5, tx = t & 31;
    int row0 = blockIdx.x * 64;
    float acc[8][4];
#pragma unroll
    for (int r = 0; r < 8; ++r)
#pragma unroll
        for (int c = 0; c < 4; ++c) acc[r][c] = 0.f;

    for (int kc = 0; kc < 128; kc += 32) {
#pragma unroll
        for (int i = 0; i < 2; ++i) {
            int v = t * 2 + i;
            int row = v >> 3, k4 = (v & 7) << 2;
            float4 av = make_float4(0.f, 0.f, 0.f, 0.f);
            int gr = row0 + row;
            if (gr < n) av = *(const float4*)&A[gr * 128 + kc + k4];
            As[k4 + 0][row] = av.x;
            As[k4 + 1][row] = av.y;
            As[k4 + 2][row] = av.z;
            As[k4 + 3][row] = av.w;
        }
#pragma unroll
        for (int i = 0; i < 4; ++i) {
            int v = i * 256 + t;
            *(float4*)&Ws[v * 4] = *(const float4*)&W[kc * 128 + v * 4];
        }
        __syncthreads();
#pragma unroll
        for (int k = 0; k < 32; ++k) {
            float4 alo = *(float4*)&As[k][ty * 8];
            float4 ahi = *(float4*)&As[k][ty * 8 + 4];
            float4 bv  = *(float4*)&Ws[k * 128 + tx * 4];
            float a[8] = {alo.x, alo.y, alo.z, alo.w, ahi.x, ahi.y, ahi.z, ahi.w};
#pragma unroll
            for (int r = 0; r < 8; ++r) {
                acc[r][0] += a[r] * bv.x;
                acc[r][1] += a[r] * bv.y;
                acc[r][2] += a[r] * bv.z;
                acc[r][3] += a[r] * bv.w;
            }
        }
        __syncthreads();
    }
#pragma unroll
    for (int r = 0; r < 8; ++r) {
        int row = row0 + ty * 8 + r;
        if (row < n) {
            float d = dinv[row];
            ushort4 o;
            o.x = f2bf(acc[r][0] * d);
            o.y = f2bf(acc[r][1] * d);
            o.z = f2bf(acc[r][2] * d);
            o.w = f2bf(acc[r][3] * d);
            *(ushort4*)&tb[(size_t)row * 128 + tx * 4] = o;
        }
    }
}

// ---------------- pull-aggregate (bf16 gather, fp32 accumulate) ----------------
__global__ __launch_bounds__(256) void k_pull(const unsigned short* __restrict__ ts,
                                              const int* __restrict__ csr,
                                              const int* __restrict__ rowstart,
                                              const float* __restrict__ dinv,
                                              const float* __restrict__ bias,
                                              float* __restrict__ outp, int n, int do_relu) {
    int wid = (int)((blockIdx.x * blockDim.x + threadIdx.x) >> 6);
    int lane = threadIdx.x & 63;
    if (wid >= n) return;
    int f = lane * 2;
    unsigned int v = *(const unsigned int*)&ts[(size_t)wid * 128 + f];   // self term
    float ax = __uint_as_float(v << 16);
    float ay = __uint_as_float(v & 0xFFFF0000u);
    int e1 = rowstart[wid + 1];
    int e = rowstart[wid];
    for (; e + 4 <= e1; e += 4) {
        int s0 = csr[e], s1 = csr[e + 1], s2 = csr[e + 2], s3 = csr[e + 3];
        unsigned int v0 = *(const unsigned int*)&ts[(size_t)s0 * 128 + f];
        unsigned int v1 = *(const unsigned int*)&ts[(size_t)s1 * 128 + f];
        unsigned int v2 = *(const unsigned int*)&ts[(size_t)s2 * 128 + f];
        unsigned int v3 = *(const unsigned int*)&ts[(size_t)s3 * 128 + f];
        ax += __uint_as_float(v0 << 16) + __uint_as_float(v1 << 16) +
              __uint_as_float(v2 << 16) + __uint_as_float(v3 << 16);
        ay += __uint_as_float(v0 & 0xFFFF0000u) + __uint_as_float(v1 & 0xFFFF0000u) +
              __uint_as_float(v2 & 0xFFFF0000u) + __uint_as_float(v3 & 0xFFFF0000u);
    }
    for (; e < e1; ++e) {
        int s = csr[e];
        unsigned int vv = *(const unsigned int*)&ts[(size_t)s * 128 + f];
        ax += __uint_as_float(vv << 16);
        ay += __uint_as_float(vv & 0xFFFF0000u);
    }
    float d = dinv[wid];
    float ox = ax * d + bias[f];
    float oy = ay * d + bias[f + 1];
    if (do_relu) { ox = fmaxf(ox, 0.f); oy = fmaxf(oy, 0.f); }
    *(float2*)&outp[(size_t)wid * 128 + f] = make_float2(ox, oy);
}

// ---------------- mean-pool ----------------
__global__ __launch_bounds__(128) void k_pool(const float* __restrict__ h,
                                              const int* __restrict__ batch,
                                              float* __restrict__ sums, int n) {
    int f = threadIdx.x;
    int n0 = blockIdx.x * 64;
    int n1 = min(n0 + 64, n);
    float run = 0.f;
    int cur = batch[n0];
    for (int i = n0; i < n1; ++i) {
        int g = batch[i];
        if (g != cur) {
            atomicAdd(&sums[cur * 128 + f], run);
            run = 0.f;
            cur = g;
        }
        run += h[(size_t)i * 128 + f];
    }
    atomicAdd(&sums[cur * 128 + f], run);
}

__global__ void k_counts(const int* __restrict__ batch, float* __restrict__ counts, int n) {
    int g = threadIdx.x;
    int lo = 0, hi = n;
    while (lo < hi) { int mid = (lo + hi) >> 1; if (batch[mid] < g) lo = mid + 1; else hi = mid; }
    int a = lo;
    lo = 0; hi = n;
    int key = g + 1;
    while (lo < hi) { int mid = (lo + hi) >> 1; if (batch[mid] < key) lo = mid + 1; else hi = mid; }
    counts[g] = (float)(lo - a);
}

// ---------------- head MLP ----------------
__global__ __launch_bounds__(512) void k_head(const float* __restrict__ sums,
                                              const float* __restrict__ counts,
                                              const float* __restrict__ Wo1,
                                              const float* __restrict__ bo1,
                                              const float* __restrict__ Wo2,
                                              const float* __restrict__ bo2,
                                              float* __restrict__ outp) {
    __shared__ float P[NG * 128];
    __shared__ float Z[NG * 64];
    int t = threadIdx.x;
    for (int i = t; i < NG * 128; i += 512) {
        int g = i >> 7;
        P[i] = sums[i] / fmaxf(counts[g], 1.f);
    }
    __syncthreads();
    for (int i = t; i < NG * 64; i += 512) {
        int g = i >> 6, c = i & 63;
        float s = bo1[c];
        for (int k = 0; k < 128; ++k) s += P[g * 128 + k] * Wo1[k * 64 + c];
        Z[i] = fmaxf(s, 0.f);
    }
    __syncthreads();
    for (int i = t; i < NG * OUTF; i += 512) {
        int g = i >> 5, c = i & 31;
        float s = bo2[c];
        for (int k = 0; k < 64; ++k) s += Z[g * 64 + k] * Wo2[k * 32 + c];
        outp[i] = s;
    }
}

extern "C" void kernel_launch(void* const* d_in, const int* in_sizes, int n_in,
                              void* d_out, int out_size, void* d_ws, size_t ws_size,
                              hipStream_t stream) {
    const float* x    = (const float*)d_in[0];
    const int*   ei   = (const int*)d_in[1];
    const int*   batch= (const int*)d_in[2];
    const float* W1   = (const float*)d_in[3];
    const float* b1   = (const float*)d_in[4];
    const float* W2   = (const float*)d_in[5];
    const float* b2   = (const float*)d_in[6];
    const float* W3   = (const float*)d_in[7];
    const float* b3   = (const float*)d_in[8];
    const float* Wo1  = (const float*)d_in[9];
    const float* bo1  = (const float*)d_in[10];
    const float* Wo2  = (const float*)d_in[11];
    const float* bo2  = (const float*)d_in[12];

    int n = in_sizes[0] / DIN;
    int e = in_sizes[1] / 2;
    const int* esrc = ei;
    const int* edst = ei + e;

    char* ws = (char*)d_ws;
    auto align = [](size_t v) { return (v + 255) & ~(size_t)255; };
    size_t off = 0;
    int*   deg      = (int*)(ws + off); off = align(off + sizeof(int) * n);
    int*   rowstart = (int*)(ws + off); off = align(off + sizeof(int) * (n + 1));
    int*   csr      = (int*)(ws + off); off = align(off + sizeof(int) * e);
    int2*  ebuf     = (int2*)(ws + off); off = align(off + sizeof(int2) * (size_t)e);
    float* dinv     = (float*)(ws + off); off = align(off + sizeof(float) * n);
    unsigned short* tbuf = (unsigned short*)(ws + off); off = align(off + sizeof(short) * (size_t)n * HF);
    float* buf0     = (float*)(ws + off); off = align(off + sizeof(float) * (size_t)n * HF);
    float* sums     = (float*)(ws + off); off = align(off + sizeof(float) * NG * HF);
    float* counts   = (float*)(ws + off); off = align(off + sizeof(float) * NG);
    int*   bsum     = (int*)(ws + off); off = align(off + sizeof(int) * 512);
    int*   boff     = (int*)(ws + off); off = align(off + sizeof(int) * 512);
    int*   bcur     = (int*)(ws + off); off = align(off + sizeof(int) * 1024);

    int tb = 256;
    int gb_n = (n + tb - 1) / tb;
    int gb_e = (e + tb - 1) / tb;
    int nbs = (n + SCH - 1) / SCH;            // scan blocks
    int nbk = (n + NPB - 1) >> BSHIFT;        // buckets (196)

    k_init<<<gb_n, tb, 0, stream>>>(deg, sums, n, NG * HF);
    k_deg<<<gb_e, tb, 0, stream>>>(edst, deg, e);
    k_dinv<<<gb_n, tb, 0, stream>>>(deg, dinv, n);
    k_blksum<<<nbs, 256, 0, stream>>>(deg, bsum, n);
    k_scanb<<<1, 256, 0, stream>>>(bsum, boff, nbs, rowstart, n);
    k_fixup<<<nbs, 256, 0, stream>>>(deg, boff, rowstart, n);
    k_binit<<<(nbk + 255) / 256, 256, 0, stream>>>(rowstart, bcur, n, nbk);
    k_pass1<<<(e + 256 * P1_VPT - 1) / (256 * P1_VPT), 256, 0, stream>>>(esrc, edst, bcur, ebuf, e);
    k_pass2<<<nbk, 256, 0, stream>>>(ebuf, rowstart, csr, n);

    int gemm_grid = (n + 63) / 64;
    int pull_grid = (int)(((size_t)n * 64 + tb - 1) / tb);

    k_gemm<<<gemm_grid, 256, 0, stream>>>(x, W1, dinv, tbuf, n);
    k_pull<<<pull_grid, 256, 0, stream>>>(tbuf, csr, rowstart, dinv, b1, buf0, n, 1);
    k_gemm<<<gemm_grid, 256, 0, stream>>>(buf0, W2, dinv, tbuf, n);
    k_pull<<<pull_grid, 256, 0, stream>>>(tbuf, csr, rowstart, dinv, b2, buf0, n, 1);
    k_gemm<<<gemm_grid, 256, 0, stream>>>(buf0, W3, dinv, tbuf, n);
    k_pull<<<pull_grid, 256, 0, stream>>>(tbuf, csr, rowstart, dinv, b3, buf0, n, 0);

    k_pool<<<(n + 63) / 64, 128, 0, stream>>>(buf0, batch, sums, n);
    k_counts<<<1, 64, 0, stream>>>(batch, counts, n);
    k_head<<<1, 512, 0, stream>>>(sums, counts, Wo1, bo1, Wo2, bo2, (float*)d_out);
}

// Round 5
// 595.937 us; speedup vs baseline: 1.7566x; 1.0571x over previous
//
#include <hip/hip_runtime.h>

#define DIN 128
#define HF  128
#define OUTF 32
#define NG  64
#define SCH 2048     // scan elements per block
#define NPB 512      // nodes per bucket
#define BSHIFT 9
#define P1_VPT 16    // edges per thread in pass1
#define P2_CAP 14336 // staged csr span capacity (ints) per bucket

static __device__ __forceinline__ unsigned short f2bf(float f) {
    unsigned int u = __float_as_uint(f);
    u = (u + 0x7FFFu + ((u >> 16) & 1u)) >> 16;   // RNE
    return (unsigned short)u;
}

// ---------------- init ----------------
__global__ void k_init(int* __restrict__ deg, float* __restrict__ sums, int n, int m) {
    int i = blockIdx.x * blockDim.x + threadIdx.x;
    if (i < n) deg[i] = 0;
    if (i < m) sums[i] = 0.f;
}

// ---------------- degree ----------------
__global__ void k_deg(const int* __restrict__ dst, int* __restrict__ deg, int e) {
    int i = blockIdx.x * blockDim.x + threadIdx.x;
    if (i < e) atomicAdd(&deg[dst[i]], 1);
}

__global__ void k_dinv(const int* __restrict__ deg, float* __restrict__ dinv, int n) {
    int i = blockIdx.x * blockDim.x + threadIdx.x;
    if (i < n) dinv[i] = rsqrtf((float)deg[i] + 1.0f);   // +1 = self loop
}

// ---------------- multi-block exclusive scan (deg -> rowstart) ----------------
__global__ __launch_bounds__(256) void k_blksum(const int* __restrict__ deg,
                                                int* __restrict__ bsum, int n) {
    __shared__ int s[256];
    int b = blockIdx.x, t = threadIdx.x;
    int base = b * SCH + t * 8;
    int sum = 0;
    if (base + 8 <= n) {
        int4 a = *(const int4*)&deg[base];
        int4 c = *(const int4*)&deg[base + 4];
        sum = a.x + a.y + a.z + a.w + c.x + c.y + c.z + c.w;
    } else {
        for (int i = base; i < min(base + 8, n); ++i) sum += deg[i];
    }
    s[t] = sum;
    __syncthreads();
    for (int off = 128; off > 0; off >>= 1) {
        if (t < off) s[t] += s[t + off];
        __syncthreads();
    }
    if (t == 0) bsum[b] = s[0];
}

__global__ __launch_bounds__(256) void k_scanb(const int* __restrict__ bsum,
                                               int* __restrict__ boff, int nb,
                                               int* __restrict__ rowstart, int n) {
    __shared__ int s[256];
    int t = threadIdx.x;
    int v = (t < nb) ? bsum[t] : 0;
    s[t] = v;
    __syncthreads();
    for (int off = 1; off < 256; off <<= 1) {
        int u = (t >= off) ? s[t - off] : 0;
        __syncthreads();
        s[t] += u;
        __syncthreads();
    }
    if (t < nb) boff[t] = s[t] - v;
    if (t == 255) rowstart[n] = s[255];
}

// fixup also seeds bucket cursors (bcur) at bucket-boundary nodes
__global__ __launch_bounds__(256) void k_fixup(const int* __restrict__ deg,
                                               const int* __restrict__ boff,
                                               int* __restrict__ rowstart,
                                               int* __restrict__ bcur, int n) {
    __shared__ int s[256];
    int b = blockIdx.x, t = threadIdx.x;
    int base = b * SCH + t * 8;
    int d[8];
    int sum = 0;
#pragma unroll
    for (int i = 0; i < 8; ++i) {
        int idx = base + i;
        d[i] = (idx < n) ? deg[idx] : 0;
        sum += d[i];
    }
    s[t] = sum;
    __syncthreads();
    for (int off = 1; off < 256; off <<= 1) {
        int u = (t >= off) ? s[t - off] : 0;
        __syncthreads();
        s[t] += u;
        __syncthreads();
    }
    int excl = boff[b] + s[t] - sum;
    int r[8];
#pragma unroll
    for (int i = 0; i < 8; ++i) { r[i] = excl; excl += d[i]; }
    if (base + 8 <= n) {
        *(int4*)&rowstart[base]     = make_int4(r[0], r[1], r[2], r[3]);
        *(int4*)&rowstart[base + 4] = make_int4(r[4], r[5], r[6], r[7]);
    } else {
        for (int i = 0; i < 8; ++i) {
            int idx = base + i;
            if (idx < n) rowstart[idx] = r[i];
        }
    }
    // base is a multiple of 8; bucket boundaries are multiples of 512
    if ((base & (NPB - 1)) == 0 && base < n) bcur[base >> BSHIFT] = r[0];
}

// ---------------- pass1: coarse bucket (dst>>9), LDS-ranked grouped writes ----
// packed entry: (dst & 511) << 20 | src   (requires n < 2^20)
__global__ __launch_bounds__(256) void k_pass1(const int* __restrict__ esrc,
                                               const int* __restrict__ edst,
                                               int* __restrict__ bcur,
                                               int* __restrict__ ebuf, int e) {
    __shared__ int hist[256];
    __shared__ int base[256];
    int t = threadIdx.x;
    int c0 = blockIdx.x * (256 * P1_VPT);
    hist[t] = 0;
    __syncthreads();
    int s[P1_VPT], d[P1_VPT], r[P1_VPT];
#pragma unroll
    for (int i = 0; i < P1_VPT; ++i) {
        int idx = c0 + t + i * 256;
        if (idx < e) {
            s[i] = esrc[idx];
            d[i] = edst[idx];
            r[i] = atomicAdd(&hist[d[i] >> BSHIFT], 1);
        }
    }
    __syncthreads();
    int cnt = hist[t];
    base[t] = (cnt > 0) ? atomicAdd(&bcur[t], cnt) : 0;
    __syncthreads();
#pragma unroll
    for (int i = 0; i < P1_VPT; ++i) {
        int idx = c0 + t + i * 256;
        if (idx < e)
            ebuf[base[d[i] >> BSHIFT] + r[i]] = ((d[i] & (NPB - 1)) << 20) | s[i];
    }
}

// ---------------- pass2: per-bucket LDS-staged fine scatter, coalesced csr ----
__global__ __launch_bounds__(256) void k_pass2(const int* __restrict__ ebuf,
                                               const int* __restrict__ rowstart,
                                               int* __restrict__ csr, int n) {
    __shared__ int lcur[NPB];
    __shared__ int lbuf[P2_CAP];
    int b = blockIdx.x;
    int node0 = b << BSHIFT;
    int node1 = min(node0 + NPB, n);
    int t = threadIdx.x;
    int bbase = rowstart[node0];
    int bend = rowstart[node1];
    int span = bend - bbase;
    for (int j = t; j < node1 - node0; j += 256) lcur[j] = rowstart[node0 + j] - bbase;
    __syncthreads();
    if (span <= P2_CAP) {
        for (int i = t; i < span; i += 256) {
            int v = ebuf[bbase + i];
            int lp = atomicAdd(&lcur[v >> 20], 1);
            lbuf[lp] = v & 0xFFFFF;
        }
        __syncthreads();
        for (int i = t; i < span; i += 256) csr[bbase + i] = lbuf[i];
    } else {  // safety fallback
        for (int i = t; i < span; i += 256) {
            int v = ebuf[bbase + i];
            int lp = atomicAdd(&lcur[v >> 20], 1);
            csr[bbase + lp] = v & 0xFFFFF;
        }
    }
}

// ---------------- GEMM: tb[r] = bf16((A[r] @ W) * dinv[r]) ----------------
__global__ __launch_bounds__(256) void k_gemm(const float* __restrict__ A,
                                              const float* __restrict__ W,
                                              const float* __restrict__ dinv,
                                              unsigned short* __restrict__ tb, int n) {
    __shared__ float As[32][68];
    __shared__ float Ws[32 * 128];
    int t = threadIdx.x;
    int ty = t >> 5, tx = t & 31;
    int row0 = blockIdx.x * 64;
    float acc[8][4];
#pragma unroll
    for (int r = 0; r < 8; ++r)
#pragma unroll
        for (int c = 0; c < 4; ++c) acc[r][c] = 0.f;

    for (int kc = 0; kc < 128; kc += 32) {
#pragma unroll
        for (int i = 0; i < 2; ++i) {
            int v = t * 2 + i;
            int row = v >> 3, k4 = (v & 7) << 2;
            float4 av = make_float4(0.f, 0.f, 0.f, 0.f);
            int gr = row0 + row;
            if (gr < n) av = *(const float4*)&A[gr * 128 + kc + k4];
            As[k4 + 0][row] = av.x;
            As[k4 + 1][row] = av.y;
            As[k4 + 2][row] = av.z;
            As[k4 + 3][row] = av.w;
        }
#pragma unroll
        for (int i = 0; i < 4; ++i) {
            int v = i * 256 + t;
            *(float4*)&Ws[v * 4] = *(const float4*)&W[kc * 128 + v * 4];
        }
        __syncthreads();
#pragma unroll
        for (int k = 0; k < 32; ++k) {
            float4 alo = *(float4*)&As[k][ty * 8];
            float4 ahi = *(float4*)&As[k][ty * 8 + 4];
            float4 bv  = *(float4*)&Ws[k * 128 + tx * 4];
            float a[8] = {alo.x, alo.y, alo.z, alo.w, ahi.x, ahi.y, ahi.z, ahi.w};
#pragma unroll
            for (int r = 0; r < 8; ++r) {
                acc[r][0] += a[r] * bv.x;
                acc[r][1] += a[r] * bv.y;
                acc[r][2] += a[r] * bv.z;
                acc[r][3] += a[r] * bv.w;
            }
        }
        __syncthreads();
    }
#pragma unroll
    for (int r = 0; r < 8; ++r) {
        int row = row0 + ty * 8 + r;
        if (row < n) {
            float d = dinv[row];
            ushort4 o;
            o.x = f2bf(acc[r][0] * d);
            o.y = f2bf(acc[r][1] * d);
            o.z = f2bf(acc[r][2] * d);
            o.w = f2bf(acc[r][3] * d);
            *(ushort4*)&tb[(size_t)row * 128 + tx * 4] = o;
        }
    }
}

// ---------------- pull-aggregate: 4 nodes/wave, 16 lanes/node, 16B/lane ----
// 16 outstanding gathers per wave (4 streams x unroll 4) to hide HBM/L3 latency
__global__ __launch_bounds__(256) void k_pull(const unsigned short* __restrict__ ts,
                                              const int* __restrict__ csr,
                                              const int* __restrict__ rowstart,
                                              const float* __restrict__ dinv,
                                              const float* __restrict__ bias,
                                              float* __restrict__ outp, int n, int do_relu) {
    int tid = blockIdx.x * blockDim.x + threadIdx.x;
    int sg = tid >> 4;        // node id (one 16-lane subgroup per node)
    int sl = tid & 15;        // sublane: owns features sl*8 .. sl*8+7
    if (sg >= n) return;
    int f0 = sl * 8;

    uint4 sv = *(const uint4*)&ts[(size_t)sg * 128 + f0];   // self term
    float a0 = __uint_as_float(sv.x << 16), a1 = __uint_as_float(sv.x & 0xFFFF0000u);
    float a2 = __uint_as_float(sv.y << 16), a3 = __uint_as_float(sv.y & 0xFFFF0000u);
    float a4 = __uint_as_float(sv.z << 16), a5 = __uint_as_float(sv.z & 0xFFFF0000u);
    float a6 = __uint_as_float(sv.w << 16), a7 = __uint_as_float(sv.w & 0xFFFF0000u);

    int e  = rowstart[sg];
    int e1 = rowstart[sg + 1];
    for (; e + 4 <= e1; e += 4) {
        int s0 = csr[e], s1 = csr[e + 1], s2 = csr[e + 2], s3 = csr[e + 3];
        uint4 v0 = *(const uint4*)&ts[(size_t)s0 * 128 + f0];
        uint4 v1 = *(const uint4*)&ts[(size_t)s1 * 128 + f0];
        uint4 v2 = *(const uint4*)&ts[(size_t)s2 * 128 + f0];
        uint4 v3 = *(const uint4*)&ts[(size_t)s3 * 128 + f0];
        a0 += __uint_as_float(v0.x << 16) + __uint_as_float(v1.x << 16) +
              __uint_as_float(v2.x << 16) + __uint_as_float(v3.x << 16);
        a1 += __uint_as_float(v0.x & 0xFFFF0000u) + __uint_as_float(v1.x & 0xFFFF0000u) +
              __uint_as_float(v2.x & 0xFFFF0000u) + __uint_as_float(v3.x & 0xFFFF0000u);
        a2 += __uint_as_float(v0.y << 16) + __uint_as_float(v1.y << 16) +
              __uint_as_float(v2.y << 16) + __uint_as_float(v3.y << 16);
        a3 += __uint_as_float(v0.y & 0xFFFF0000u) + __uint_as_float(v1.y & 0xFFFF0000u) +
              __uint_as_float(v2.y & 0xFFFF0000u) + __uint_as_float(v3.y & 0xFFFF0000u);
        a4 += __uint_as_float(v0.z << 16) + __uint_as_float(v1.z << 16) +
              __uint_as_float(v2.z << 16) + __uint_as_float(v3.z << 16);
        a5 += __uint_as_float(v0.z & 0xFFFF0000u) + __uint_as_float(v1.z & 0xFFFF0000u) +
              __uint_as_float(v2.z & 0xFFFF0000u) + __uint_as_float(v3.z & 0xFFFF0000u);
        a6 += __uint_as_float(v0.w << 16) + __uint_as_float(v1.w << 16) +
              __uint_as_float(v2.w << 16) + __uint_as_float(v3.w << 16);
        a7 += __uint_as_float(v0.w & 0xFFFF0000u) + __uint_as_float(v1.w & 0xFFFF0000u) +
              __uint_as_float(v2.w & 0xFFFF0000u) + __uint_as_float(v3.w & 0xFFFF0000u);
    }
    for (; e < e1; ++e) {
        int s = csr[e];
        uint4 v = *(const uint4*)&ts[(size_t)s * 128 + f0];
        a0 += __uint_as_float(v.x << 16);  a1 += __uint_as_float(v.x & 0xFFFF0000u);
        a2 += __uint_as_float(v.y << 16);  a3 += __uint_as_float(v.y & 0xFFFF0000u);
        a4 += __uint_as_float(v.z << 16);  a5 += __uint_as_float(v.z & 0xFFFF0000u);
        a6 += __uint_as_float(v.w << 16);  a7 += __uint_as_float(v.w & 0xFFFF0000u);
    }
    float d = dinv[sg];
    float4 bl = *(const float4*)&bias[f0];
    float4 bh = *(const float4*)&bias[f0 + 4];
    float4 ol = make_float4(a0 * d + bl.x, a1 * d + bl.y, a2 * d + bl.z, a3 * d + bl.w);
    float4 oh = make_float4(a4 * d + bh.x, a5 * d + bh.y, a6 * d + bh.z, a7 * d + bh.w);
    if (do_relu) {
        ol.x = fmaxf(ol.x, 0.f); ol.y = fmaxf(ol.y, 0.f);
        ol.z = fmaxf(ol.z, 0.f); ol.w = fmaxf(ol.w, 0.f);
        oh.x = fmaxf(oh.x, 0.f); oh.y = fmaxf(oh.y, 0.f);
        oh.z = fmaxf(oh.z, 0.f); oh.w = fmaxf(oh.w, 0.f);
    }
    *(float4*)&outp[(size_t)sg * 128 + f0]     = ol;
    *(float4*)&outp[(size_t)sg * 128 + f0 + 4] = oh;
}

// ---------------- mean-pool ----------------
__global__ __launch_bounds__(128) void k_pool(const float* __restrict__ h,
                                              const int* __restrict__ batch,
                                              float* __restrict__ sums, int n) {
    int f = threadIdx.x;
    int n0 = blockIdx.x * 64;
    int n1 = min(n0 + 64, n);
    float run = 0.f;
    int cur = batch[n0];
    for (int i = n0; i < n1; ++i) {
        int g = batch[i];
        if (g != cur) {
            atomicAdd(&sums[cur * 128 + f], run);
            run = 0.f;
            cur = g;
        }
        run += h[(size_t)i * 128 + f];
    }
    atomicAdd(&sums[cur * 128 + f], run);
}

// ---------------- head MLP (counts fused in) ----------------
__global__ __launch_bounds__(512) void k_head(const float* __restrict__ sums,
                                              const int* __restrict__ batch, int n,
                                              const float* __restrict__ Wo1,
                                              const float* __restrict__ bo1,
                                              const float* __restrict__ Wo2,
                                              const float* __restrict__ bo2,
                                              float* __restrict__ outp) {
    __shared__ float cnt[NG];
    __shared__ float P[NG * 128];
    __shared__ float Z[NG * 64];
    int t = threadIdx.x;
    if (t < NG) {
        int g = t;
        int lo = 0, hi = n;
        while (lo < hi) { int mid = (lo + hi) >> 1; if (batch[mid] < g) lo = mid + 1; else hi = mid; }
        int a = lo;
        lo = 0; hi = n;
        int key = g + 1;
        while (lo < hi) { int mid = (lo + hi) >> 1; if (batch[mid] < key) lo = mid + 1; else hi = mid; }
        cnt[g] = (float)(lo - a);
    }
    __syncthreads();
    for (int i = t; i < NG * 128; i += 512) {
        int g = i >> 7;
        P[i] = sums[i] / fmaxf(cnt[g], 1.f);
    }
    __syncthreads();
    for (int i = t; i < NG * 64; i += 512) {
        int g = i >> 6, c = i & 63;
        float s = bo1[c];
        for (int k = 0; k < 128; ++k) s += P[g * 128 + k] * Wo1[k * 64 + c];
        Z[i] = fmaxf(s, 0.f);
    }
    __syncthreads();
    for (int i = t; i < NG * OUTF; i += 512) {
        int g = i >> 5, c = i & 31;
        float s = bo2[c];
        for (int k = 0; k < 64; ++k) s += Z[g * 64 + k] * Wo2[k * 32 + c];
        outp[i] = s;
    }
}

extern "C" void kernel_launch(void* const* d_in, const int* in_sizes, int n_in,
                              void* d_out, int out_size, void* d_ws, size_t ws_size,
                              hipStream_t stream) {
    const float* x    = (const float*)d_in[0];
    const int*   ei   = (const int*)d_in[1];
    const int*   batch= (const int*)d_in[2];
    const float* W1   = (const float*)d_in[3];
    const float* b1   = (const float*)d_in[4];
    const float* W2   = (const float*)d_in[5];
    const float* b2   = (const float*)d_in[6];
    const float* W3   = (const float*)d_in[7];
    const float* b3   = (const float*)d_in[8];
    const float* Wo1  = (const float*)d_in[9];
    const float* bo1  = (const float*)d_in[10];
    const float* Wo2  = (const float*)d_in[11];
    const float* bo2  = (const float*)d_in[12];

    int n = in_sizes[0] / DIN;
    int e = in_sizes[1] / 2;
    const int* esrc = ei;
    const int* edst = ei + e;

    char* ws = (char*)d_ws;
    auto align = [](size_t v) { return (v + 255) & ~(size_t)255; };
    size_t off = 0;
    int*   deg      = (int*)(ws + off); off = align(off + sizeof(int) * n);
    int*   rowstart = (int*)(ws + off); off = align(off + sizeof(int) * (n + 1));
    int*   csr      = (int*)(ws + off); off = align(off + sizeof(int) * e);
    int*   ebuf     = (int*)(ws + off); off = align(off + sizeof(int) * (size_t)e);
    float* dinv     = (float*)(ws + off); off = align(off + sizeof(float) * n);
    unsigned short* tbuf = (unsigned short*)(ws + off); off = align(off + sizeof(short) * (size_t)n * HF);
    float* buf0     = (float*)(ws + off); off = align(off + sizeof(float) * (size_t)n * HF);
    float* sums     = (float*)(ws + off); off = align(off + sizeof(float) * NG * HF);
    int*   bsum     = (int*)(ws + off); off = align(off + sizeof(int) * 512);
    int*   boff     = (int*)(ws + off); off = align(off + sizeof(int) * 512);
    int*   bcur     = (int*)(ws + off); off = align(off + sizeof(int) * 1024);

    int tb = 256;
    int gb_n = (n + tb - 1) / tb;
    int gb_e = (e + tb - 1) / tb;
    int nbs = (n + SCH - 1) / SCH;            // scan blocks
    int nbk = (n + NPB - 1) >> BSHIFT;        // buckets

    k_init<<<gb_n, tb, 0, stream>>>(deg, sums, n, NG * HF);
    k_deg<<<gb_e, tb, 0, stream>>>(edst, deg, e);
    k_dinv<<<gb_n, tb, 0, stream>>>(deg, dinv, n);
    k_blksum<<<nbs, 256, 0, stream>>>(deg, bsum, n);
    k_scanb<<<1, 256, 0, stream>>>(bsum, boff, nbs, rowstart, n);
    k_fixup<<<nbs, 256, 0, stream>>>(deg, boff, rowstart, bcur, n);
    k_pass1<<<(e + 256 * P1_VPT - 1) / (256 * P1_VPT), 256, 0, stream>>>(esrc, edst, bcur, ebuf, e);
    k_pass2<<<nbk, 256, 0, stream>>>(ebuf, rowstart, csr, n);

    int gemm_grid = (n + 63) / 64;
    int pull_grid = (int)(((size_t)n * 16 + tb - 1) / tb);

    k_gemm<<<gemm_grid, 256, 0, stream>>>(x, W1, dinv, tbuf, n);
    k_pull<<<pull_grid, 256, 0, stream>>>(tbuf, csr, rowstart, dinv, b1, buf0, n, 1);
    k_gemm<<<gemm_grid, 256, 0, stream>>>(buf0, W2, dinv, tbuf, n);
    k_pull<<<pull_grid, 256, 0, stream>>>(tbuf, csr, rowstart, dinv, b2, buf0, n, 1);
    k_gemm<<<gemm_grid, 256, 0, stream>>>(buf0, W3, dinv, tbuf, n);
    k_pull<<<pull_grid, 256, 0, stream>>>(tbuf, csr, rowstart, dinv, b3, buf0, n, 0);

    k_pool<<<(n + 63) / 64, 128, 0, stream>>>(buf0, batch, sums, n);
    k_head<<<1, 512, 0, stream>>>(sums, batch, n, Wo1, bo1, Wo2, bo2, (float*)d_out);
}

// Round 6
// 498.017 us; speedup vs baseline: 2.1020x; 1.1966x over previous
//
#include <hip/hip_runtime.h>

#define HF  128
#define OUTF 32
#define NG  64
#define NPB 512      // nodes per bucket
#define BSHIFT 9
#define P1_VPT 16    // edges per thread in pass1
#define P2_CAP 14336 // staged csr span capacity (ints) per bucket

typedef short bf16x8 __attribute__((ext_vector_type(8)));
typedef float f32x4  __attribute__((ext_vector_type(4)));

static __device__ __forceinline__ unsigned short f2bf(float f) {
    unsigned int u = __float_as_uint(f);
    u = (u + 0x7FFFu + ((u >> 16) & 1u)) >> 16;   // RNE
    return (unsigned short)u;
}
static __device__ __forceinline__ float bf2f(unsigned short u) {
    return __uint_as_float((unsigned int)u << 16);
}
static __device__ __forceinline__ void gload_lds16(const void* g, void* l) {
    __builtin_amdgcn_global_load_lds(
        (const __attribute__((address_space(1))) unsigned int*)g,
        (__attribute__((address_space(3))) unsigned int*)l, 16, 0, 0);
}

// ---------------- init: zero sums, bucket counts, hb pad rows ----------------
__global__ void k_init(float* __restrict__ sums, int* __restrict__ gcnt,
                       unsigned short* __restrict__ hbpad, int padus) {
    int i = blockIdx.x * blockDim.x + threadIdx.x;
    if (i < NG * HF) sums[i] = 0.f;
    if (i < 256) gcnt[i] = 0;
    if (i < padus) hbpad[i] = 0;
}

// ---------------- bucket counts via LDS histogram ----------------
__global__ __launch_bounds__(256) void k_bcnt(const int* __restrict__ edst,
                                              int* __restrict__ gcnt, int e) {
    __shared__ int h[256];
    int t = threadIdx.x;
    h[t] = 0;
    __syncthreads();
    int base = blockIdx.x * 4096 + t * 16;
    if (base + 16 <= e) {
#pragma unroll
        for (int i = 0; i < 4; ++i) {
            int4 d = *(const int4*)&edst[base + i * 4];
            atomicAdd(&h[d.x >> BSHIFT], 1);
            atomicAdd(&h[d.y >> BSHIFT], 1);
            atomicAdd(&h[d.z >> BSHIFT], 1);
            atomicAdd(&h[d.w >> BSHIFT], 1);
        }
    } else {
        for (int i = base; i < min(base + 16, e); ++i) atomicAdd(&h[edst[i] >> BSHIFT], 1);
    }
    __syncthreads();
    if (h[t]) atomicAdd(&gcnt[t], h[t]);
}

// ---------------- scan bucket counts -> goff, bcur; rowstart[n]=E ----------
__global__ __launch_bounds__(256) void k_bscan(const int* __restrict__ gcnt,
                                               int* __restrict__ goff,
                                               int* __restrict__ bcur,
                                               int* __restrict__ rowstart, int n, int nbk) {
    __shared__ int s[256];
    int t = threadIdx.x;
    int v = (t < nbk) ? gcnt[t] : 0;
    s[t] = v;
    __syncthreads();
    for (int off = 1; off < 256; off <<= 1) {
        int u = (t >= off) ? s[t - off] : 0;
        __syncthreads();
        s[t] += u;
        __syncthreads();
    }
    if (t == 0) goff[0] = 0;
    goff[t + 1] = s[t];
    bcur[t] = s[t] - v;
    if (t == 255) rowstart[n] = s[255];
}

// ---------------- pass1: coarse bucket (dst>>9), LDS-ranked grouped writes ----
// packed entry: (dst & 511) << 20 | src   (requires n < 2^20)
__global__ __launch_bounds__(256) void k_pass1(const int* __restrict__ esrc,
                                               const int* __restrict__ edst,
                                               int* __restrict__ bcur,
                                               int* __restrict__ ebuf, int e) {
    __shared__ int hist[256];
    __shared__ int base[256];
    int t = threadIdx.x;
    int c0 = blockIdx.x * (256 * P1_VPT);
    hist[t] = 0;
    __syncthreads();
    int s[P1_VPT], d[P1_VPT], r[P1_VPT];
#pragma unroll
    for (int i = 0; i < P1_VPT; ++i) {
        int idx = c0 + t + i * 256;
        if (idx < e) {
            s[i] = esrc[idx];
            d[i] = edst[idx];
            r[i] = atomicAdd(&hist[d[i] >> BSHIFT], 1);
        }
    }
    __syncthreads();
    int cnt = hist[t];
    base[t] = (cnt > 0) ? atomicAdd(&bcur[t], cnt) : 0;
    __syncthreads();
#pragma unroll
    for (int i = 0; i < P1_VPT; ++i) {
        int idx = c0 + t + i * 256;
        if (idx < e)
            ebuf[base[d[i] >> BSHIFT] + r[i]] = ((d[i] & (NPB - 1)) << 20) | s[i];
    }
}

// ---- pass2 (fused): per-bucket degree count + scan + rowstart + dinv + scatter
__global__ __launch_bounds__(256) void k_pass2(const int* __restrict__ ebuf,
                                               const int* __restrict__ goff,
                                               int* __restrict__ rowstart,
                                               int* __restrict__ csr,
                                               float* __restrict__ dinv, int n) {
    __shared__ int ldeg[NPB];
    __shared__ int lexc[NPB];
    __shared__ int s[256];
    __shared__ int lbuf[P2_CAP];
    int b = blockIdx.x, t = threadIdx.x;
    int node0 = b << BSHIFT;
    int nn = min(NPB, n - node0);
    int bbase = goff[b];
    int span = goff[b + 1] - bbase;
    ldeg[t] = 0;
    ldeg[t + 256] = 0;
    __syncthreads();
    for (int i = t; i < span; i += 256) atomicAdd(&ldeg[ebuf[bbase + i] >> 20], 1);
    __syncthreads();
    int d0 = ldeg[2 * t], d1 = ldeg[2 * t + 1];
    s[t] = d0 + d1;
    __syncthreads();
    for (int off = 1; off < 256; off <<= 1) {
        int u = (t >= off) ? s[t - off] : 0;
        __syncthreads();
        s[t] += u;
        __syncthreads();
    }
    int exc = s[t] - (d0 + d1);
    lexc[2 * t] = exc;
    lexc[2 * t + 1] = exc + d0;
    if (2 * t < nn) {
        rowstart[node0 + 2 * t] = bbase + exc;
        dinv[node0 + 2 * t] = rsqrtf((float)d0 + 1.0f);
    }
    if (2 * t + 1 < nn) {
        rowstart[node0 + 2 * t + 1] = bbase + exc + d0;
        dinv[node0 + 2 * t + 1] = rsqrtf((float)d1 + 1.0f);
    }
    __syncthreads();
    if (span <= P2_CAP) {
        for (int i = t; i < span; i += 256) {
            int v = ebuf[bbase + i];
            int lp = atomicAdd(&lexc[v >> 20], 1);
            lbuf[lp] = v & 0xFFFFF;
        }
        __syncthreads();
        for (int i = t; i < span; i += 256) csr[bbase + i] = lbuf[i];
    } else {  // safety fallback
        for (int i = t; i < span; i += 256) {
            int v = ebuf[bbase + i];
            int lp = atomicAdd(&lexc[v >> 20], 1);
            csr[bbase + lp] = v & 0xFFFFF;
        }
    }
}

// ---------------- W prep: transpose + bf16 hi/lo split (lo pre-swizzled) ----
__global__ __launch_bounds__(256) void k_wprep(const float* __restrict__ W1,
                                               const float* __restrict__ W2,
                                               const float* __restrict__ W3,
                                               unsigned short* __restrict__ wh,
                                               unsigned short* __restrict__ wl) {
    const float* W = (blockIdx.x == 0) ? W1 : ((blockIdx.x == 1) ? W2 : W3);
    unsigned short* whb = wh + blockIdx.x * 16384;
    unsigned short* wlb = wl + blockIdx.x * 16384;
    int t = threadIdx.x;
    int c = t & 127, kh = (t >> 7) * 64;
    int sw = (c & 7) << 3;
    for (int k = kh; k < kh + 64; ++k) {
        float v = W[k * HF + c];
        unsigned short hi = f2bf(v);
        float r = v - bf2f(hi);
        whb[c * HF + k] = hi;
        wlb[c * HF + (k ^ sw)] = f2bf(r);
    }
}

// ---------------- MFMA GEMM: T = bf16((A @ W) * dinv), 128x128 tile ----------
// A: fp32 (layer 1, Afp) or bf16 padded (layers 2/3, Abf). W split: hi in
// registers (plain [c][k]), lo in LDS (pre-swizzled global, linear gload_lds).
__global__ __launch_bounds__(256) void k_gemm(const float* __restrict__ Afp,
                                              const unsigned short* __restrict__ Abf,
                                              const unsigned short* __restrict__ wthi,
                                              const unsigned short* __restrict__ wtlo,
                                              const float* __restrict__ dinv,
                                              unsigned short* __restrict__ T, int n) {
    __shared__ unsigned short As[16384];  // swizzled [row][k] bf16
    __shared__ unsigned short Wl[16384];  // swizzled [col][k] bf16
    int t = threadIdx.x;
    int l = t & 63, w = t >> 6;
    int row0 = blockIdx.x * 128;
    int lm = l & 15, lg = l >> 4;

    // stage W-lo (pre-swizzled source -> linear LDS)
#pragma unroll
    for (int p = 0; p < 8; ++p)
        gload_lds16(&wtlo[(size_t)(p * 256 + t) * 8], &Wl[(size_t)(p * 256 + w * 64) * 8]);

    // stage A (swizzled image)
    if (Afp) {
#pragma unroll
        for (int p = 0; p < 8; ++p) {
            int cid = p * 256 + t;
            int row = cid >> 4, ch = cid & 15;
            int gr = row0 + row;
            float4 f0 = make_float4(0.f, 0.f, 0.f, 0.f), f1 = f0;
            if (gr < n) {
                f0 = *(const float4*)&Afp[(size_t)gr * HF + ch * 8];
                f1 = *(const float4*)&Afp[(size_t)gr * HF + ch * 8 + 4];
            }
            uint4 u;
            u.x = f2bf(f0.x) | ((unsigned)f2bf(f0.y) << 16);
            u.y = f2bf(f0.z) | ((unsigned)f2bf(f0.w) << 16);
            u.z = f2bf(f1.x) | ((unsigned)f2bf(f1.y) << 16);
            u.w = f2bf(f1.z) | ((unsigned)f2bf(f1.w) << 16);
            *(uint4*)((char*)As + row * 256 + ((ch * 16) ^ ((row & 7) << 4))) = u;
        }
    } else {
#pragma unroll
        for (int p = 0; p < 8; ++p) {
            int cid = p * 256 + t;
            int row = cid >> 4, ch = cid & 15;
            const char* src = (const char*)Abf + (size_t)(row0 + row) * 256 +
                              ((ch * 16) ^ ((row & 7) << 4));
            gload_lds16(src, (char*)As + (size_t)(p * 256 + w * 64) * 16);
        }
    }

    // W-hi fragments into registers (L2-hot global reads)
    int wr = (w >> 1) * 64, wc = (w & 1) * 64;
    bf16x8 bh[4][4];
#pragma unroll
    for (int ni = 0; ni < 4; ++ni)
#pragma unroll
        for (int kk = 0; kk < 4; ++kk)
            bh[ni][kk] = *(const bf16x8*)&wthi[(size_t)(wc + ni * 16 + lm) * HF + kk * 32 + lg * 8];

    __syncthreads();

    f32x4 acc[4][4];
#pragma unroll
    for (int mi = 0; mi < 4; ++mi)
#pragma unroll
        for (int ni = 0; ni < 4; ++ni) {
            f32x4 z = {0.f, 0.f, 0.f, 0.f};
            acc[mi][ni] = z;
        }

    int swz = (l & 7) << 4;
#pragma unroll
    for (int kk = 0; kk < 4; ++kk) {
        int kb = (kk * 64 + lg * 16) ^ swz;
        bf16x8 a[4], bl[4];
#pragma unroll
        for (int mi = 0; mi < 4; ++mi)
            a[mi] = *(bf16x8*)((char*)As + (wr + mi * 16 + lm) * 256 + kb);
#pragma unroll
        for (int ni = 0; ni < 4; ++ni)
            bl[ni] = *(bf16x8*)((char*)Wl + (wc + ni * 16 + lm) * 256 + kb);
#pragma unroll
        for (int mi = 0; mi < 4; ++mi)
#pragma unroll
            for (int ni = 0; ni < 4; ++ni) {
                acc[mi][ni] = __builtin_amdgcn_mfma_f32_16x16x32_bf16(a[mi], bh[ni][kk], acc[mi][ni], 0, 0, 0);
                acc[mi][ni] = __builtin_amdgcn_mfma_f32_16x16x32_bf16(a[mi], bl[ni], acc[mi][ni], 0, 0, 0);
            }
    }

    // epilogue: scale by dinv, convert bf16, store (T is padded; no row guard)
#pragma unroll
    for (int mi = 0; mi < 4; ++mi) {
        int rbase = row0 + wr + mi * 16 + lg * 4;
        f32x4 dv = *(const f32x4*)&dinv[rbase];
#pragma unroll
        for (int ni = 0; ni < 4; ++ni) {
            int col = wc + ni * 16 + lm;
#pragma unroll
            for (int j = 0; j < 4; ++j)
                T[(size_t)(rbase + j) * HF + col] = f2bf(acc[mi][ni][j] * dv[j]);
        }
    }
}

// ---------------- pull-aggregate: 4 nodes/wave, 16 lanes/node, unroll 8 ----
__global__ __launch_bounds__(256) void k_pull(const unsigned short* __restrict__ ts,
                                              const int* __restrict__ csr,
                                              const int* __restrict__ rowstart,
                                              const float* __restrict__ dinv,
                                              const float* __restrict__ bias,
                                              unsigned short* __restrict__ outb,
                                              float* __restrict__ outf, int n) {
    int tid = blockIdx.x * blockDim.x + threadIdx.x;
    int sg = tid >> 4;
    int sl = tid & 15;
    if (sg >= n) return;
    int f0 = sl * 8;

    uint4 sv = *(const uint4*)&ts[(size_t)sg * HF + f0];
    float a0 = __uint_as_float(sv.x << 16), a1 = __uint_as_float(sv.x & 0xFFFF0000u);
    float a2 = __uint_as_float(sv.y << 16), a3 = __uint_as_float(sv.y & 0xFFFF0000u);
    float a4 = __uint_as_float(sv.z << 16), a5 = __uint_as_float(sv.z & 0xFFFF0000u);
    float a6 = __uint_as_float(sv.w << 16), a7 = __uint_as_float(sv.w & 0xFFFF0000u);

    int e = rowstart[sg];
    int e1 = rowstart[sg + 1];
#define ACC8(v) \
    a0 += __uint_as_float(v.x << 16); a1 += __uint_as_float(v.x & 0xFFFF0000u); \
    a2 += __uint_as_float(v.y << 16); a3 += __uint_as_float(v.y & 0xFFFF0000u); \
    a4 += __uint_as_float(v.z << 16); a5 += __uint_as_float(v.z & 0xFFFF0000u); \
    a6 += __uint_as_float(v.w << 16); a7 += __uint_as_float(v.w & 0xFFFF0000u);
    for (; e + 8 <= e1; e += 8) {
        int s0 = csr[e], s1 = csr[e + 1], s2 = csr[e + 2], s3 = csr[e + 3];
        int s4 = csr[e + 4], s5 = csr[e + 5], s6 = csr[e + 6], s7 = csr[e + 7];
        uint4 v0 = *(const uint4*)&ts[(size_t)s0 * HF + f0];
        uint4 v1 = *(const uint4*)&ts[(size_t)s1 * HF + f0];
        uint4 v2 = *(const uint4*)&ts[(size_t)s2 * HF + f0];
        uint4 v3 = *(const uint4*)&ts[(size_t)s3 * HF + f0];
        uint4 v4 = *(const uint4*)&ts[(size_t)s4 * HF + f0];
        uint4 v5 = *(const uint4*)&ts[(size_t)s5 * HF + f0];
        uint4 v6 = *(const uint4*)&ts[(size_t)s6 * HF + f0];
        uint4 v7 = *(const uint4*)&ts[(size_t)s7 * HF + f0];
        ACC8(v0) ACC8(v1) ACC8(v2) ACC8(v3) ACC8(v4) ACC8(v5) ACC8(v6) ACC8(v7)
    }
    for (; e < e1; ++e) {
        int sx = csr[e];
        uint4 v = *(const uint4*)&ts[(size_t)sx * HF + f0];
        ACC8(v)
    }
#undef ACC8
    float d = dinv[sg];
    float4 blv = *(const float4*)&bias[f0];
    float4 bhv = *(const float4*)&bias[f0 + 4];
    float o0 = a0 * d + blv.x, o1 = a1 * d + blv.y, o2 = a2 * d + blv.z, o3 = a3 * d + blv.w;
    float o4 = a4 * d + bhv.x, o5 = a5 * d + bhv.y, o6 = a6 * d + bhv.z, o7 = a7 * d + bhv.w;
    if (outb) {  // hidden layers: relu + bf16
        o0 = fmaxf(o0, 0.f); o1 = fmaxf(o1, 0.f); o2 = fmaxf(o2, 0.f); o3 = fmaxf(o3, 0.f);
        o4 = fmaxf(o4, 0.f); o5 = fmaxf(o5, 0.f); o6 = fmaxf(o6, 0.f); o7 = fmaxf(o7, 0.f);
        uint4 u;
        u.x = f2bf(o0) | ((unsigned)f2bf(o1) << 16);
        u.y = f2bf(o2) | ((unsigned)f2bf(o3) << 16);
        u.z = f2bf(o4) | ((unsigned)f2bf(o5) << 16);
        u.w = f2bf(o6) | ((unsigned)f2bf(o7) << 16);
        *(uint4*)&outb[(size_t)sg * HF + f0] = u;
    } else {     // last layer: fp32, no relu
        *(float4*)&outf[(size_t)sg * HF + f0] = make_float4(o0, o1, o2, o3);
        *(float4*)&outf[(size_t)sg * HF + f0 + 4] = make_float4(o4, o5, o6, o7);
    }
}

// ---------------- mean-pool ----------------
__global__ __launch_bounds__(128) void k_pool(const float* __restrict__ h,
                                              const int* __restrict__ batch,
                                              float* __restrict__ sums, int n) {
    int f = threadIdx.x;
    int n0 = blockIdx.x * 64;
    int n1 = min(n0 + 64, n);
    float run = 0.f;
    int cur = batch[n0];
    for (int i = n0; i < n1; ++i) {
        int g = batch[i];
        if (g != cur) {
            atomicAdd(&sums[cur * HF + f], run);
            run = 0.f;
            cur = g;
        }
        run += h[(size_t)i * HF + f];
    }
    atomicAdd(&sums[cur * HF + f], run);
}

// ---------------- head MLP (counts fused) ----------------
__global__ __launch_bounds__(512) void k_head(const float* __restrict__ sums,
                                              const int* __restrict__ batch, int n,
                                              const float* __restrict__ Wo1,
                                              const float* __restrict__ bo1,
                                              const float* __restrict__ Wo2,
                                              const float* __restrict__ bo2,
                                              float* __restrict__ outp) {
    __shared__ float cnt[NG];
    __shared__ float P[NG * 128];
    __shared__ float Z[NG * 64];
    int t = threadIdx.x;
    if (t < NG) {
        int g = t;
        int lo = 0, hi = n;
        while (lo < hi) { int mid = (lo + hi) >> 1; if (batch[mid] < g) lo = mid + 1; else hi = mid; }
        int a = lo;
        lo = 0; hi = n;
        int key = g + 1;
        while (lo < hi) { int mid = (lo + hi) >> 1; if (batch[mid] < key) lo = mid + 1; else hi = mid; }
        cnt[g] = (float)(lo - a);
    }
    __syncthreads();
    for (int i = t; i < NG * 128; i += 512) {
        int g = i >> 7;
        P[i] = sums[i] / fmaxf(cnt[g], 1.f);
    }
    __syncthreads();
    for (int i = t; i < NG * 64; i += 512) {
        int g = i >> 6, c = i & 63;
        float s = bo1[c];
        for (int k = 0; k < 128; ++k) s += P[g * 128 + k] * Wo1[k * 64 + c];
        Z[i] = fmaxf(s, 0.f);
    }
    __syncthreads();
    for (int i = t; i < NG * OUTF; i += 512) {
        int g = i >> 5, c = i & 31;
        float s = bo2[c];
        for (int k = 0; k < 64; ++k) s += Z[g * 64 + k] * Wo2[k * 32 + c];
        outp[i] = s;
    }
}

extern "C" void kernel_launch(void* const* d_in, const int* in_sizes, int n_in,
                              void* d_out, int out_size, void* d_ws, size_t ws_size,
                              hipStream_t stream) {
    const float* x    = (const float*)d_in[0];
    const int*   ei   = (const int*)d_in[1];
    const int*   batch= (const int*)d_in[2];
    const float* W1   = (const float*)d_in[3];
    const float* b1   = (const float*)d_in[4];
    const float* W2   = (const float*)d_in[5];
    const float* b2   = (const float*)d_in[6];
    const float* W3   = (const float*)d_in[7];
    const float* b3   = (const float*)d_in[8];
    const float* Wo1  = (const float*)d_in[9];
    const float* bo1  = (const float*)d_in[10];
    const float* Wo2  = (const float*)d_in[11];
    const float* bo2  = (const float*)d_in[12];

    int n = in_sizes[0] / HF;
    int e = in_sizes[1] / 2;
    const int* esrc = ei;
    const int* edst = ei + e;
    int npad = ((n + 127) / 128) * 128;

    char* ws = (char*)d_ws;
    auto align = [](size_t v) { return (v + 255) & ~(size_t)255; };
    size_t off = 0;
    int*   rowstart = (int*)(ws + off); off = align(off + sizeof(int) * (n + 1));
    int*   csr      = (int*)(ws + off); off = align(off + sizeof(int) * e);
    int*   ebuf     = (int*)(ws + off); off = align(off + sizeof(int) * (size_t)e);
    float* dinv     = (float*)(ws + off); off = align(off + sizeof(float) * npad);
    unsigned short* tbuf = (unsigned short*)(ws + off); off = align(off + sizeof(short) * (size_t)npad * HF);
    unsigned short* hb   = (unsigned short*)(ws + off); off = align(off + sizeof(short) * (size_t)npad * HF);
    float* buf0     = (float*)(ws + off); off = align(off + sizeof(float) * (size_t)n * HF);
    float* sums     = (float*)(ws + off); off = align(off + sizeof(float) * NG * HF);
    int*   gcnt     = (int*)(ws + off); off = align(off + sizeof(int) * 256);
    int*   goff     = (int*)(ws + off); off = align(off + sizeof(int) * 257);
    int*   bcur     = (int*)(ws + off); off = align(off + sizeof(int) * 256);
    unsigned short* wh = (unsigned short*)(ws + off); off = align(off + sizeof(short) * 3 * 16384);
    unsigned short* wl = (unsigned short*)(ws + off); off = align(off + sizeof(short) * 3 * 16384);

    int nbk = (n + NPB - 1) >> BSHIFT;
    int padus = (npad - n) * HF;

    k_init<<<64, 256, 0, stream>>>(sums, gcnt, hb + (size_t)n * HF, padus);
    k_bcnt<<<(e + 4095) / 4096, 256, 0, stream>>>(edst, gcnt, e);
    k_bscan<<<1, 256, 0, stream>>>(gcnt, goff, bcur, rowstart, n, nbk);
    k_pass1<<<(e + 256 * P1_VPT - 1) / (256 * P1_VPT), 256, 0, stream>>>(esrc, edst, bcur, ebuf, e);
    k_pass2<<<nbk, 256, 0, stream>>>(ebuf, goff, rowstart, csr, dinv, n);
    k_wprep<<<3, 256, 0, stream>>>(W1, W2, W3, wh, wl);

    int gemm_grid = npad / 128;
    int pull_grid = (int)(((size_t)n * 16 + 255) / 256);

    k_gemm<<<gemm_grid, 256, 0, stream>>>(x, hb, wh, wl, dinv, tbuf, n);
    k_pull<<<pull_grid, 256, 0, stream>>>(tbuf, csr, rowstart, dinv, b1, hb, nullptr, n);
    k_gemm<<<gemm_grid, 256, 0, stream>>>(nullptr, hb, wh + 16384, wl + 16384, dinv, tbuf, n);
    k_pull<<<pull_grid, 256, 0, stream>>>(tbuf, csr, rowstart, dinv, b2, hb, nullptr, n);
    k_gemm<<<gemm_grid, 256, 0, stream>>>(nullptr, hb, wh + 32768, wl + 32768, dinv, tbuf, n);
    k_pull<<<pull_grid, 256, 0, stream>>>(tbuf, csr, rowstart, dinv, b3, nullptr, buf0, n);

    k_pool<<<(n + 63) / 64, 128, 0, stream>>>(buf0, batch, sums, n);
    k_head<<<1, 512, 0, stream>>>(sums, batch, n, Wo1, bo1, Wo2, bo2, (float*)d_out);
}